// Round 16
// baseline (494.907 us; speedup 1.0000x reference)
//
#include <hip/hip_runtime.h>
#include <stdint.h>
#include <math.h>

// Problem constants
#define B_ 4
#define H_ 16
#define DM_ 1024
#define NQ_ 1024
#define NK_ 1024
// D_K = D_V = 64

typedef __attribute__((ext_vector_type(4))) float f32x4;
typedef __attribute__((ext_vector_type(4))) int   s32x4;
typedef __attribute__((ext_vector_type(4))) short s16x4;
typedef __attribute__((ext_vector_type(8))) short s16x8;

#define MFMA(a, b, c) __builtin_amdgcn_mfma_f32_16x16x32_bf16(a, b, c, 0, 0, 0)

static __device__ __forceinline__ short f2bf(float f) {
  union { float f; uint32_t u; } v; v.f = f;
  uint32_t r = (v.u + 0x7FFFu + ((v.u >> 16) & 1u)) >> 16;  // RNE
  return (short)(uint16_t)r;
}

static __device__ __forceinline__ float bf2f(short s) {
  union { uint32_t u; float f; } v;
  v.u = ((uint32_t)(uint16_t)s) << 16;
  return v.f;
}

static __device__ __forceinline__ void gload_lds16(const void* g, void* s) {
  __builtin_amdgcn_global_load_lds(
      (const __attribute__((address_space(1))) uint32_t*)g,
      (__attribute__((address_space(3))) uint32_t*)s, 16, 0, 0);
}

// ---------------------------------------------------------------- f32 -> bf16 (4 weight matrices, one launch)
__global__ void k_cvt4(const float* __restrict__ a, const float* __restrict__ b,
                       const float* __restrict__ c, const float* __restrict__ d,
                       short* __restrict__ o0, short* __restrict__ o1,
                       short* __restrict__ o2, short* __restrict__ o3) {
  const int i = (blockIdx.x * 256 + threadIdx.x) * 4;
  const float* src; short* dst;
  switch (blockIdx.y) {
    case 0: src = a; dst = o0; break;
    case 1: src = b; dst = o1; break;
    case 2: src = c; dst = o2; break;
    default: src = d; dst = o3; break;
  }
  f32x4 v = *(const f32x4*)(src + i);
  s16x4 o;
  o.x = f2bf(v.x); o.y = f2bf(v.y); o.z = f2bf(v.z); o.w = f2bf(v.w);
  *(s16x4*)(dst + i) = o;
}

// ---------------------------------------------------------------- GEMM
// C[m][n] = sum_k A[m][k] * Bw[n][k] + bias[n]
// mode 0: A = f32 (fused cvt in staging), out bf16 (B,H,N,64)   (Q, K proj)
// mode 1: A = f32 (fused cvt in staging), out bf16 (B,H,64,N)   (V proj, transposed)
// mode 2: A = bf16 (gload_lds path), out f32 M x 1024           (output proj)
// R16: modes 0/1 read the f32 activations DIRECTLY and convert during
// reg-staging->ds_write (same XOR-chunk swizzle the ds_read expects) —
// kills 3 k_cvt launches + the 96MB Xq/Xk/Xv HBM round-trip.
__global__ __launch_bounds__(256, 2) void k_gemm(
    const void* __restrict__ Asrc, const short* __restrict__ Bw,
    const float* __restrict__ bias, void* __restrict__ outp, int mode) {
  __shared__ short As[128 * 64];
  __shared__ short Bs[128 * 64];
  const int tid = threadIdx.x;
  const int w = tid >> 6, l = tid & 63;
  const int wm = w >> 1, wn = w & 1;
  const int lr = l & 15, lg = l >> 4;
  const int m0 = blockIdx.x * 128, n0 = blockIdx.y * 128;

  f32x4 acc[4][4] = {};

  for (int kt = 0; kt < 16; ++kt) {
    __syncthreads();
    if (mode < 2) {
      // A: f32 -> bf16 reg-staging. Pass p: 16-thread groups read 256B rows.
      const float* Af = (const float*)Asrc;
#pragma unroll
      for (int p = 0; p < 8; ++p) {
        const int e = p * 1024 + tid * 4;
        const int row = e >> 6, col = e & 63;
        const f32x4 v = *(const f32x4*)(Af + (size_t)(m0 + row) * 1024 + kt * 64 + col);
        s16x4 pk;
        pk.x = f2bf(v.x); pk.y = f2bf(v.y); pk.z = f2bf(v.z); pk.w = f2bf(v.w);
        *(s16x4*)((char*)As + row * 128 + (((col >> 3) ^ (row & 7)) << 4) + (col & 4) * 2) = pk;
      }
    } else {
      const short* A = (const short*)Asrc;
#pragma unroll
      for (int q = 0; q < 4; ++q) {
        const int slot = (w * 4 + q) * 64 + l;
        const int row = slot >> 3;
        const int chunk = (slot & 7) ^ (row & 7);
        const size_t goff = (size_t)row * 1024 + (size_t)kt * 64 + chunk * 8;
        gload_lds16(A + (size_t)m0 * 1024 + goff, (char*)As + (w * 4 + q) * 1024);
      }
    }
#pragma unroll
    for (int q = 0; q < 4; ++q) {
      const int slot = (w * 4 + q) * 64 + l;
      const int row = slot >> 3;
      const int chunk = (slot & 7) ^ (row & 7);
      const size_t goff = (size_t)row * 1024 + (size_t)kt * 64 + chunk * 8;
      gload_lds16(Bw + (size_t)n0 * 1024 + goff, (char*)Bs + (w * 4 + q) * 1024);
    }
    asm volatile("s_waitcnt vmcnt(0)");
    __syncthreads();
#pragma unroll
    for (int ks = 0; ks < 2; ++ks) {
      s16x8 af[4], bfr[4];
#pragma unroll
      for (int mi = 0; mi < 4; ++mi) {
        const int row = wm * 64 + mi * 16 + lr;
        const int chunk = (ks * 4 + lg) ^ (row & 7);
        af[mi] = *(const s16x8*)(As + row * 64 + chunk * 8);
      }
#pragma unroll
      for (int ni = 0; ni < 4; ++ni) {
        const int row = wn * 64 + ni * 16 + lr;
        const int chunk = (ks * 4 + lg) ^ (row & 7);
        bfr[ni] = *(const s16x8*)(Bs + row * 64 + chunk * 8);
      }
#pragma unroll
      for (int mi = 0; mi < 4; ++mi)
#pragma unroll
        for (int ni = 0; ni < 4; ++ni)
          acc[mi][ni] = MFMA(af[mi], bfr[ni], acc[mi][ni]);
    }
  }

  // Epilogue. C frag: row=(lg*4+r), col=lr within each 16x16.
#pragma unroll
  for (int mi = 0; mi < 4; ++mi) {
#pragma unroll
    for (int ni = 0; ni < 4; ++ni) {
      const int gm0 = m0 + wm * 64 + mi * 16 + lg * 4;
      const int gc = n0 + wn * 64 + ni * 16 + lr;
      const float bv = bias[gc];
      if (mode == 2) {
        float* o = (float*)outp;
#pragma unroll
        for (int r = 0; r < 4; ++r)
          o[(size_t)(gm0 + r) * 1024 + gc] = acc[mi][ni][r] + bv;
      } else if (mode == 0) {
        short* o = (short*)outp;
        const int h = gc >> 6, d = gc & 63;
#pragma unroll
        for (int r = 0; r < 4; ++r) {
          const int gm = gm0 + r;
          const int b = gm >> 10, np = gm & 1023;
          o[((size_t)(b * 16 + h) * 1024 + np) * 64 + d] = f2bf(acc[mi][ni][r] + bv);
        }
      } else {  // mode 1: transposed V, pack 4 consecutive n-positions as 8B store
        short* o = (short*)outp;
        const int h = gc >> 6, d = gc & 63;
        const int b = gm0 >> 10, np0 = gm0 & 1023;
        s16x4 pk;
        pk.x = f2bf(acc[mi][ni][0] + bv);
        pk.y = f2bf(acc[mi][ni][1] + bv);
        pk.z = f2bf(acc[mi][ni][2] + bv);
        pk.w = f2bf(acc[mi][ni][3] + bv);
        *(s16x4*)(o + ((size_t)(b * 16 + h) * 64 + d) * 1024 + np0) = pk;
      }
    }
  }
}

// ---------------------------------------------------------------- fused attention (no-split flash, rotated kt-walk)
// R15 champion, byte-identical. Grid (NQ/64, B*H); 4 waves; wave owns 16
// q-rows; walks all 16 key-tiles with per-BLOCK kt-rotation (breaks lockstep
// channel camping, +13% R9). Falsified levers: occupancy (21-46% neutral),
// register pipelining, vectorization, burst shape, phase separation, NT
// hints, per-wave rotation. k_attn sits at ~2.9 TB/s on its mandatory
// ~700MB mixed stream — practical wall.
__global__ __launch_bounds__(256, 3) void k_attn(
    const short* __restrict__ qws, const short* __restrict__ kws,
    const short* __restrict__ vtws,
    const float* __restrict__ attw, const int* __restrict__ attm,
    float* __restrict__ att_map, short* __restrict__ aout) {
  __shared__ f32x4 s_lds[4 * 256];       // per wave: 16 rows x 16 f32x4 chunks (4KB)
  __shared__ short p_lds[4 * 16 * 64];   // per wave: 16 x 64 bf16 (2KB), swizzled
  __shared__ float st_lds[4 * 16];       // per wave: per-row corr / inv broadcast
  const int tid = threadIdx.x;
  const int w = tid >> 6, l = tid & 63;
  const int lr = l & 15, lg = l >> 4;
  const int bh = blockIdx.y;                 // b*16 + h
  const int q0 = blockIdx.x * 64 + w * 16;   // this wave's first q row
  f32x4* const sw = s_lds + w * 256;
  char* const pw = (char*)p_lds + w * 2048;
  float* const stw = st_lds + w * 16;

  // Q fragments (B-operand of swapped QK^T: col = lr = q, kk = lg*8 + j)
  const short* qb = qws + ((size_t)bh * NQ_ + q0 + lr) * 64 + lg * 8;
  const s16x8 qf0 = *(const s16x8*)(qb);
  const s16x8 qf1 = *(const s16x8*)(qb + 32);

  f32x4 o[4] = {};
  float m4[4], l4[4];                    // linear-domain state: row = it*4 + lg
#pragma unroll
  for (int it = 0; it < 4; ++it) { m4[it] = -3.0e38f; l4[it] = 0.0f; }

  // linear-domain global base: row q0 + lg (+ it*4), col lr*4
  const size_t linBase = ((size_t)bh * NQ_ + q0 + lg) * (size_t)NK_ + lr * 4;

  const int rot = (blockIdx.x + bh) & 15;  // per-BLOCK kt-phase decorrelation

  for (int t = 0; t < 16; ++t) {
    const int kt = (rot + t) & 15;
    // ---- S^T = K Q^T: lane holds S[k=fn*16+lg*4+{0..3}][q=lr]
    f32x4 s[4];
    const short* kb0 = kws + ((size_t)bh * NK_ + kt * 64 + lr) * 64 + lg * 8;
#pragma unroll
    for (int fn = 0; fn < 4; ++fn) {
      const short* kb = kb0 + fn * 1024;
      f32x4 z = {};
      z = MFMA(*(const s16x8*)kb, qf0, z);
      z = MFMA(*(const s16x8*)(kb + 32), qf1, z);
      s[fn] = z;
    }
    // ---- S -> per-wave LDS: row = q = lr, k-chunk = fn*4+lg, swizzle ^row
#pragma unroll
    for (int fn = 0; fn < 4; ++fn)
      sw[lr * 16 + ((fn * 4 + lg) ^ lr)] = s[fn];
    asm volatile("s_waitcnt lgkmcnt(0)" ::: "memory");
    __builtin_amdgcn_sched_barrier(0);
    // ---- linear phase: issue all S reads + att loads up front (MLP)
    f32x4 sv4[4], wv4[4];
    s32x4 mv4[4];
#pragma unroll
    for (int it = 0; it < 4; ++it) {
      const int q = it * 4 + lg;
      sv4[it] = sw[q * 16 + (lr ^ q)];
      const size_t ga = linBase + (size_t)(it * 4) * NK_ + kt * 64;
      wv4[it] = *(const f32x4*)(attw + ga);
      mv4[it] = *(const s32x4*)(attm + ga);
    }
#pragma unroll
    for (int it = 0; it < 4; ++it) {
      const int q = it * 4 + lg;
      f32x4 sv;
#pragma unroll
      for (int j = 0; j < 4; ++j) sv[j] = sv4[it][j] * 0.125f;
      const size_t ga = linBase + (size_t)(it * 4) * NK_ + kt * 64;
      *(f32x4*)(att_map + ga) = sv;            // 256B-contiguous per 16-lane group
      float p[4];
#pragma unroll
      for (int j = 0; j < 4; ++j)
        p[j] = mv4[it][j] ? sv[j] * wv4[it][j] : -1.0e30f;
      // row reduce within the 16 consecutive lanes owning this row
      float t2 = fmaxf(fmaxf(p[0], p[1]), fmaxf(p[2], p[3]));
      t2 = fmaxf(t2, __shfl_xor(t2, 1, 64));
      t2 = fmaxf(t2, __shfl_xor(t2, 2, 64));
      t2 = fmaxf(t2, __shfl_xor(t2, 4, 64));
      t2 = fmaxf(t2, __shfl_xor(t2, 8, 64));
      const float mn = fmaxf(m4[it], t2);
      const float corr = __expf(m4[it] - mn);
      m4[it] = mn;
      float rs = 0.0f;
#pragma unroll
      for (int j = 0; j < 4; ++j) { p[j] = __expf(p[j] - mn); rs += p[j]; }
      rs += __shfl_xor(rs, 1, 64);
      rs += __shfl_xor(rs, 2, 64);
      rs += __shfl_xor(rs, 4, 64);
      rs += __shfl_xor(rs, 8, 64);
      l4[it] = l4[it] * corr + rs;
      // P (bf16) -> p_lds in A-operand layout [q][k], 16B-chunk XOR swizzle
      s16x4 pk;
      pk.x = f2bf(p[0]); pk.y = f2bf(p[1]); pk.z = f2bf(p[2]); pk.w = f2bf(p[3]);
      *(s16x4*)(pw + q * 128 + (((lr >> 1) ^ (q & 7)) << 4) + (lr & 1) * 8) = pk;
      if (lr == 0) stw[q] = corr;              // per-row corr broadcast
    }
    asm volatile("s_waitcnt lgkmcnt(0)" ::: "memory");
    __builtin_amdgcn_sched_barrier(0);
    // ---- o rescale: o rows are q = lg*4 + r (MFMA C layout)
#pragma unroll
    for (int r = 0; r < 4; ++r) {
      const float cr = stw[lg * 4 + r];        // same-address broadcast per lg
      o[0][r] *= cr; o[1][r] *= cr; o[2][r] *= cr; o[3][r] *= cr;
    }
    // ---- PV: o += P @ V  (A = P rows q=lr, B = V^T rows dv=lr)
    const short* vb0 = vtws + ((size_t)bh * 64 + lr) * (size_t)NK_ + (size_t)kt * 64 + lg * 8;
#pragma unroll
    for (int ks = 0; ks < 2; ++ks) {
      const int chunk = (ks * 4 + lg) ^ (lr & 7);
      const s16x8 pa = *(const s16x8*)(pw + lr * 128 + chunk * 16);
#pragma unroll
      for (int g = 0; g < 4; ++g) {
        const s16x8 vf = *(const s16x8*)(vb0 + (size_t)g * 16 * NK_ + ks * 32);
        o[g] = MFMA(pa, vf, o[g]);
      }
    }
  }

  // ---- normalize and write attention output (B, NQ, H*64) bf16
  if (lr == 0) {
#pragma unroll
    for (int it = 0; it < 4; ++it) stw[it * 4 + lg] = 1.0f / l4[it];
  }
  asm volatile("s_waitcnt lgkmcnt(0)" ::: "memory");
  __builtin_amdgcn_sched_barrier(0);
  const int b = bh >> 4, h = bh & 15;
#pragma unroll
  for (int r = 0; r < 4; ++r) {
    const float inv = stw[lg * 4 + r];
    const size_t orow = ((size_t)b * NQ_ + q0 + lg * 4 + r) * 1024 + h * 64 + lr;
#pragma unroll
    for (int g = 0; g < 4; ++g)
      aout[orow + g * 16] = f2bf(o[g][r] * inv);
  }
}

// ---------------------------------------------------------------- launch
extern "C" void kernel_launch(void* const* d_in, const int* in_sizes, int n_in,
                              void* d_out, int out_size, void* d_ws, size_t ws_size,
                              hipStream_t stream) {
  const float* queries = (const float*)d_in[0];
  const float* keys    = (const float*)d_in[1];
  const float* values  = (const float*)d_in[2];
  const float* attw    = (const float*)d_in[3];
  const int*   attm    = (const int*)d_in[4];
  const float* Wq = (const float*)d_in[5];
  const float* bq = (const float*)d_in[6];
  const float* Wk = (const float*)d_in[7];
  const float* bk = (const float*)d_in[8];
  const float* Wv = (const float*)d_in[9];
  const float* bv = (const float*)d_in[10];
  const float* Wo = (const float*)d_in[11];
  const float* bo = (const float*)d_in[12];

  float* out = (float*)d_out;                              // (4,1024,1024)
  float* att_map = out + (size_t)B_ * NQ_ * DM_;           // (4,16,1024,1024)

  // Workspace layout (shorts). Total 40 MB.
  short* ws  = (short*)d_ws;
  short* WqB = ws;                   // 1024*1024 each
  short* WkB = WqB + 1048576;
  short* WvB = WkB + 1048576;
  short* WoB = WvB + 1048576;
  short* qws = WoB + 1048576;        // (B,H,NQ,64)
  short* kws = qws + 4194304;        // (B,H,NK,64)
  short* vtw = kws + 4194304;        // (B,H,64,NK)
  short* aout = vtw + 4194304;       // (B*NQ, H*64)

  // weights: one fused cvt launch (4 matrices, gridDim.y selects)
  k_cvt4<<<dim3(1024, 4), 256, 0, stream>>>(Wq, Wk, Wv, Wo, WqB, WkB, WvB, WoB);

  // projections: f32 activations read directly, cvt fused into A-staging
  dim3 gg(32, 8);
  k_gemm<<<gg, 256, 0, stream>>>(queries, WqB, bq, qws, 0);
  k_gemm<<<gg, 256, 0, stream>>>(keys,    WkB, bk, kws, 0);
  k_gemm<<<gg, 256, 0, stream>>>(values,  WvB, bv, vtw, 1);

  dim3 ga(16, 64);
  k_attn<<<ga, 256, 0, stream>>>(qws, kws, vtw, attw, attm, att_map, aout);

  k_gemm<<<gg, 256, 0, stream>>>(aout, WoB, bo, out, 2);
}

// Round 17
// 337.577 us; speedup vs baseline: 1.4661x; 1.4661x over previous
//
#include <hip/hip_runtime.h>
#include <stdint.h>
#include <math.h>

// Problem constants
#define B_ 4
#define H_ 16
#define DM_ 1024
#define NQ_ 1024
#define NK_ 1024
// D_K = D_V = 64

typedef __attribute__((ext_vector_type(4))) float f32x4;
typedef __attribute__((ext_vector_type(4))) int   s32x4;
typedef __attribute__((ext_vector_type(4))) short s16x4;
typedef __attribute__((ext_vector_type(8))) short s16x8;

#define MFMA(a, b, c) __builtin_amdgcn_mfma_f32_16x16x32_bf16(a, b, c, 0, 0, 0)

static __device__ __forceinline__ short f2bf(float f) {
  union { float f; uint32_t u; } v; v.f = f;
  uint32_t r = (v.u + 0x7FFFu + ((v.u >> 16) & 1u)) >> 16;  // RNE
  return (short)(uint16_t)r;
}

static __device__ __forceinline__ float bf2f(short s) {
  union { uint32_t u; float f; } v;
  v.u = ((uint32_t)(uint16_t)s) << 16;
  return v.f;
}

static __device__ __forceinline__ void gload_lds16(const void* g, void* s) {
  __builtin_amdgcn_global_load_lds(
      (const __attribute__((address_space(1))) uint32_t*)g,
      (__attribute__((address_space(3))) uint32_t*)s, 16, 0, 0);
}

// ---------------------------------------------------------------- f32 -> bf16, 3 activation tensors (4M elems each)
__global__ void k_cvt3(const float* __restrict__ a, const float* __restrict__ b,
                       const float* __restrict__ c,
                       short* __restrict__ o0, short* __restrict__ o1,
                       short* __restrict__ o2) {
  const int i = (blockIdx.x * 256 + threadIdx.x) * 4;
  const float* src; short* dst;
  switch (blockIdx.y) {
    case 0: src = a; dst = o0; break;
    case 1: src = b; dst = o1; break;
    default: src = c; dst = o2; break;
  }
  f32x4 v = *(const f32x4*)(src + i);
  s16x4 o;
  o.x = f2bf(v.x); o.y = f2bf(v.y); o.z = f2bf(v.z); o.w = f2bf(v.w);
  *(s16x4*)(dst + i) = o;
}

// ---------------------------------------------------------------- f32 -> bf16, 4 weight matrices (1M elems each)
__global__ void k_cvt4(const float* __restrict__ a, const float* __restrict__ b,
                       const float* __restrict__ c, const float* __restrict__ d,
                       short* __restrict__ o0, short* __restrict__ o1,
                       short* __restrict__ o2, short* __restrict__ o3) {
  const int i = (blockIdx.x * 256 + threadIdx.x) * 4;
  const float* src; short* dst;
  switch (blockIdx.y) {
    case 0: src = a; dst = o0; break;
    case 1: src = b; dst = o1; break;
    case 2: src = c; dst = o2; break;
    default: src = d; dst = o3; break;
  }
  f32x4 v = *(const f32x4*)(src + i);
  s16x4 o;
  o.x = f2bf(v.x); o.y = f2bf(v.y); o.z = f2bf(v.z); o.w = f2bf(v.w);
  *(s16x4*)(dst + i) = o;
}

// ---------------------------------------------------------------- GEMM (R15 structure: all-bf16, gload_lds both operands)
// C[m][n] = sum_k A[m][k] * Bw[n][k] + bias[n]
// mode 0: out bf16, (B,H,N,64) layout       (Q, K projections)
// mode 1: out bf16, (B,H,64,N) layout       (V projection, transposed)
// mode 2: out f32, plain M x 1024           (output projection)
// R16 lesson: fusing f32->bf16 cvt into A reg-staging made these 2.5x
// slower (Common-mistake #1: reg-staging loses global_load_lds's async
// overlap and goes VALU-bound). Keep the async path; cvt stays separate.
__global__ __launch_bounds__(256, 2) void k_gemm(
    const short* __restrict__ A, const short* __restrict__ Bw,
    const float* __restrict__ bias, void* __restrict__ outp, int mode) {
  __shared__ short As[128 * 64];
  __shared__ short Bs[128 * 64];
  const int tid = threadIdx.x;
  const int w = tid >> 6, l = tid & 63;
  const int wm = w >> 1, wn = w & 1;
  const int lr = l & 15, lg = l >> 4;
  const int m0 = blockIdx.x * 128, n0 = blockIdx.y * 128;

  f32x4 acc[4][4] = {};

  for (int kt = 0; kt < 16; ++kt) {
    __syncthreads();
#pragma unroll
    for (int q = 0; q < 4; ++q) {
      const int slot = (w * 4 + q) * 64 + l;   // 16B slot index in tile
      const int row = slot >> 3;               // 8 chunks per 128B row
      const int chunk = (slot & 7) ^ (row & 7);
      const size_t goff = (size_t)row * 1024 + (size_t)kt * 64 + chunk * 8;
      gload_lds16(A + (size_t)m0 * 1024 + goff, (char*)As + (w * 4 + q) * 1024);
      gload_lds16(Bw + (size_t)n0 * 1024 + goff, (char*)Bs + (w * 4 + q) * 1024);
    }
    asm volatile("s_waitcnt vmcnt(0)");
    __syncthreads();
#pragma unroll
    for (int ks = 0; ks < 2; ++ks) {
      s16x8 af[4], bfr[4];
#pragma unroll
      for (int mi = 0; mi < 4; ++mi) {
        const int row = wm * 64 + mi * 16 + lr;
        const int chunk = (ks * 4 + lg) ^ (row & 7);
        af[mi] = *(const s16x8*)(As + row * 64 + chunk * 8);
      }
#pragma unroll
      for (int ni = 0; ni < 4; ++ni) {
        const int row = wn * 64 + ni * 16 + lr;
        const int chunk = (ks * 4 + lg) ^ (row & 7);
        bfr[ni] = *(const s16x8*)(Bs + row * 64 + chunk * 8);
      }
#pragma unroll
      for (int mi = 0; mi < 4; ++mi)
#pragma unroll
        for (int ni = 0; ni < 4; ++ni)
          acc[mi][ni] = MFMA(af[mi], bfr[ni], acc[mi][ni]);
    }
  }

  // Epilogue. C frag: row=(lg*4+r), col=lr within each 16x16.
#pragma unroll
  for (int mi = 0; mi < 4; ++mi) {
#pragma unroll
    for (int ni = 0; ni < 4; ++ni) {
      const int gm0 = m0 + wm * 64 + mi * 16 + lg * 4;
      const int gc = n0 + wn * 64 + ni * 16 + lr;
      const float bv = bias[gc];
      if (mode == 2) {
        float* o = (float*)outp;
#pragma unroll
        for (int r = 0; r < 4; ++r)
          o[(size_t)(gm0 + r) * 1024 + gc] = acc[mi][ni][r] + bv;
      } else if (mode == 0) {
        short* o = (short*)outp;
        const int h = gc >> 6, d = gc & 63;
#pragma unroll
        for (int r = 0; r < 4; ++r) {
          const int gm = gm0 + r;
          const int b = gm >> 10, np = gm & 1023;
          o[((size_t)(b * 16 + h) * 1024 + np) * 64 + d] = f2bf(acc[mi][ni][r] + bv);
        }
      } else {  // mode 1: transposed V, pack 4 consecutive n-positions as 8B store
        short* o = (short*)outp;
        const int h = gc >> 6, d = gc & 63;
        const int b = gm0 >> 10, np0 = gm0 & 1023;
        s16x4 pk;
        pk.x = f2bf(acc[mi][ni][0] + bv);
        pk.y = f2bf(acc[mi][ni][1] + bv);
        pk.z = f2bf(acc[mi][ni][2] + bv);
        pk.w = f2bf(acc[mi][ni][3] + bv);
        *(s16x4*)(o + ((size_t)(b * 16 + h) * 64 + d) * 1024 + np0) = pk;
      }
    }
  }
}

// ---------------------------------------------------------------- fused attention (no-split flash, rotated kt-walk)
// R15 champion, byte-identical. Grid (NQ/64, B*H); 4 waves; wave owns 16
// q-rows; walks all 16 key-tiles with per-BLOCK kt-rotation (breaks lockstep
// channel camping, +13% R9). Falsified levers: occupancy (21-46% neutral),
// register pipelining, vectorization, burst shape, phase separation, NT
// hints, per-wave rotation. k_attn sits at ~2.9 TB/s on its mandatory
// ~700MB mixed stream — practical wall.
__global__ __launch_bounds__(256, 3) void k_attn(
    const short* __restrict__ qws, const short* __restrict__ kws,
    const short* __restrict__ vtws,
    const float* __restrict__ attw, const int* __restrict__ attm,
    float* __restrict__ att_map, short* __restrict__ aout) {
  __shared__ f32x4 s_lds[4 * 256];       // per wave: 16 rows x 16 f32x4 chunks (4KB)
  __shared__ short p_lds[4 * 16 * 64];   // per wave: 16 x 64 bf16 (2KB), swizzled
  __shared__ float st_lds[4 * 16];       // per wave: per-row corr / inv broadcast
  const int tid = threadIdx.x;
  const int w = tid >> 6, l = tid & 63;
  const int lr = l & 15, lg = l >> 4;
  const int bh = blockIdx.y;                 // b*16 + h
  const int q0 = blockIdx.x * 64 + w * 16;   // this wave's first q row
  f32x4* const sw = s_lds + w * 256;
  char* const pw = (char*)p_lds + w * 2048;
  float* const stw = st_lds + w * 16;

  // Q fragments (B-operand of swapped QK^T: col = lr = q, kk = lg*8 + j)
  const short* qb = qws + ((size_t)bh * NQ_ + q0 + lr) * 64 + lg * 8;
  const s16x8 qf0 = *(const s16x8*)(qb);
  const s16x8 qf1 = *(const s16x8*)(qb + 32);

  f32x4 o[4] = {};
  float m4[4], l4[4];                    // linear-domain state: row = it*4 + lg
#pragma unroll
  for (int it = 0; it < 4; ++it) { m4[it] = -3.0e38f; l4[it] = 0.0f; }

  // linear-domain global base: row q0 + lg (+ it*4), col lr*4
  const size_t linBase = ((size_t)bh * NQ_ + q0 + lg) * (size_t)NK_ + lr * 4;

  const int rot = (blockIdx.x + bh) & 15;  // per-BLOCK kt-phase decorrelation

  for (int t = 0; t < 16; ++t) {
    const int kt = (rot + t) & 15;
    // ---- S^T = K Q^T: lane holds S[k=fn*16+lg*4+{0..3}][q=lr]
    f32x4 s[4];
    const short* kb0 = kws + ((size_t)bh * NK_ + kt * 64 + lr) * 64 + lg * 8;
#pragma unroll
    for (int fn = 0; fn < 4; ++fn) {
      const short* kb = kb0 + fn * 1024;
      f32x4 z = {};
      z = MFMA(*(const s16x8*)kb, qf0, z);
      z = MFMA(*(const s16x8*)(kb + 32), qf1, z);
      s[fn] = z;
    }
    // ---- S -> per-wave LDS: row = q = lr, k-chunk = fn*4+lg, swizzle ^row
#pragma unroll
    for (int fn = 0; fn < 4; ++fn)
      sw[lr * 16 + ((fn * 4 + lg) ^ lr)] = s[fn];
    asm volatile("s_waitcnt lgkmcnt(0)" ::: "memory");
    __builtin_amdgcn_sched_barrier(0);
    // ---- linear phase: issue all S reads + att loads up front (MLP)
    f32x4 sv4[4], wv4[4];
    s32x4 mv4[4];
#pragma unroll
    for (int it = 0; it < 4; ++it) {
      const int q = it * 4 + lg;
      sv4[it] = sw[q * 16 + (lr ^ q)];
      const size_t ga = linBase + (size_t)(it * 4) * NK_ + kt * 64;
      wv4[it] = *(const f32x4*)(attw + ga);
      mv4[it] = *(const s32x4*)(attm + ga);
    }
#pragma unroll
    for (int it = 0; it < 4; ++it) {
      const int q = it * 4 + lg;
      f32x4 sv;
#pragma unroll
      for (int j = 0; j < 4; ++j) sv[j] = sv4[it][j] * 0.125f;
      const size_t ga = linBase + (size_t)(it * 4) * NK_ + kt * 64;
      *(f32x4*)(att_map + ga) = sv;            // 256B-contiguous per 16-lane group
      float p[4];
#pragma unroll
      for (int j = 0; j < 4; ++j)
        p[j] = mv4[it][j] ? sv[j] * wv4[it][j] : -1.0e30f;
      // row reduce within the 16 consecutive lanes owning this row
      float t2 = fmaxf(fmaxf(p[0], p[1]), fmaxf(p[2], p[3]));
      t2 = fmaxf(t2, __shfl_xor(t2, 1, 64));
      t2 = fmaxf(t2, __shfl_xor(t2, 2, 64));
      t2 = fmaxf(t2, __shfl_xor(t2, 4, 64));
      t2 = fmaxf(t2, __shfl_xor(t2, 8, 64));
      const float mn = fmaxf(m4[it], t2);
      const float corr = __expf(m4[it] - mn);
      m4[it] = mn;
      float rs = 0.0f;
#pragma unroll
      for (int j = 0; j < 4; ++j) { p[j] = __expf(p[j] - mn); rs += p[j]; }
      rs += __shfl_xor(rs, 1, 64);
      rs += __shfl_xor(rs, 2, 64);
      rs += __shfl_xor(rs, 4, 64);
      rs += __shfl_xor(rs, 8, 64);
      l4[it] = l4[it] * corr + rs;
      // P (bf16) -> p_lds in A-operand layout [q][k], 16B-chunk XOR swizzle
      s16x4 pk;
      pk.x = f2bf(p[0]); pk.y = f2bf(p[1]); pk.z = f2bf(p[2]); pk.w = f2bf(p[3]);
      *(s16x4*)(pw + q * 128 + (((lr >> 1) ^ (q & 7)) << 4) + (lr & 1) * 8) = pk;
      if (lr == 0) stw[q] = corr;              // per-row corr broadcast
    }
    asm volatile("s_waitcnt lgkmcnt(0)" ::: "memory");
    __builtin_amdgcn_sched_barrier(0);
    // ---- o rescale: o rows are q = lg*4 + r (MFMA C layout)
#pragma unroll
    for (int r = 0; r < 4; ++r) {
      const float cr = stw[lg * 4 + r];        // same-address broadcast per lg
      o[0][r] *= cr; o[1][r] *= cr; o[2][r] *= cr; o[3][r] *= cr;
    }
    // ---- PV: o += P @ V  (A = P rows q=lr, B = V^T rows dv=lr)
    const short* vb0 = vtws + ((size_t)bh * 64 + lr) * (size_t)NK_ + (size_t)kt * 64 + lg * 8;
#pragma unroll
    for (int ks = 0; ks < 2; ++ks) {
      const int chunk = (ks * 4 + lg) ^ (lr & 7);
      const s16x8 pa = *(const s16x8*)(pw + lr * 128 + chunk * 16);
#pragma unroll
      for (int g = 0; g < 4; ++g) {
        const s16x8 vf = *(const s16x8*)(vb0 + (size_t)g * 16 * NK_ + ks * 32);
        o[g] = MFMA(pa, vf, o[g]);
      }
    }
  }

  // ---- normalize and write attention output (B, NQ, H*64) bf16
  if (lr == 0) {
#pragma unroll
    for (int it = 0; it < 4; ++it) stw[it * 4 + lg] = 1.0f / l4[it];
  }
  asm volatile("s_waitcnt lgkmcnt(0)" ::: "memory");
  __builtin_amdgcn_sched_barrier(0);
  const int b = bh >> 4, h = bh & 15;
#pragma unroll
  for (int r = 0; r < 4; ++r) {
    const float inv = stw[lg * 4 + r];
    const size_t orow = ((size_t)b * NQ_ + q0 + lg * 4 + r) * 1024 + h * 64 + lr;
#pragma unroll
    for (int g = 0; g < 4; ++g)
      aout[orow + g * 16] = f2bf(o[g][r] * inv);
  }
}

// ---------------------------------------------------------------- launch
extern "C" void kernel_launch(void* const* d_in, const int* in_sizes, int n_in,
                              void* d_out, int out_size, void* d_ws, size_t ws_size,
                              hipStream_t stream) {
  const float* queries = (const float*)d_in[0];
  const float* keys    = (const float*)d_in[1];
  const float* values  = (const float*)d_in[2];
  const float* attw    = (const float*)d_in[3];
  const int*   attm    = (const int*)d_in[4];
  const float* Wq = (const float*)d_in[5];
  const float* bq = (const float*)d_in[6];
  const float* Wk = (const float*)d_in[7];
  const float* bk = (const float*)d_in[8];
  const float* Wv = (const float*)d_in[9];
  const float* bv = (const float*)d_in[10];
  const float* Wo = (const float*)d_in[11];
  const float* bo = (const float*)d_in[12];

  float* out = (float*)d_out;                              // (4,1024,1024)
  float* att_map = out + (size_t)B_ * NQ_ * DM_;           // (4,16,1024,1024)

  // Workspace layout (shorts). Total ~64 MB.
  short* ws  = (short*)d_ws;
  short* WqB = ws;                   // 1024*1024 each
  short* WkB = WqB + 1048576;
  short* WvB = WkB + 1048576;
  short* WoB = WvB + 1048576;
  short* Xq  = WoB + 1048576;        // 4096*1024 each
  short* Xk  = Xq + 4194304;
  short* Xv  = Xk + 4194304;
  short* qws = Xv + 4194304;         // (B,H,NQ,64)
  short* kws = qws + 4194304;        // (B,H,NK,64)
  short* vtw = kws + 4194304;        // (B,H,64,NK)
  short* aout = vtw + 4194304;       // (B*NQ, H*64)

  // cvt: 2 launches total (3 activations; 4 weights)
  k_cvt3<<<dim3(4096, 3), 256, 0, stream>>>(queries, keys, values, Xq, Xk, Xv);
  k_cvt4<<<dim3(1024, 4), 256, 0, stream>>>(Wq, Wk, Wv, Wo, WqB, WkB, WvB, WoB);

  dim3 gg(32, 8);
  k_gemm<<<gg, 256, 0, stream>>>(Xq, WqB, bq, qws, 0);
  k_gemm<<<gg, 256, 0, stream>>>(Xk, WkB, bk, kws, 0);
  k_gemm<<<gg, 256, 0, stream>>>(Xv, WvB, bv, vtw, 1);

  dim3 ga(16, 64);
  k_attn<<<ga, 256, 0, stream>>>(qws, kws, vtw, attw, attm, att_map, aout);

  k_gemm<<<gg, 256, 0, stream>>>(aout, WoB, bo, out, 2);
}

// Round 18
// 308.103 us; speedup vs baseline: 1.6063x; 1.0957x over previous
//
#include <hip/hip_runtime.h>
#include <stdint.h>
#include <math.h>

// Problem constants
#define B_ 4
#define H_ 16
#define DM_ 1024
#define NQ_ 1024
#define NK_ 1024
// D_K = D_V = 64

typedef __attribute__((ext_vector_type(4))) float f32x4;
typedef __attribute__((ext_vector_type(4))) int   s32x4;
typedef __attribute__((ext_vector_type(4))) short s16x4;
typedef __attribute__((ext_vector_type(8))) short s16x8;

#define MFMA(a, b, c) __builtin_amdgcn_mfma_f32_16x16x32_bf16(a, b, c, 0, 0, 0)

static __device__ __forceinline__ short f2bf(float f) {
  union { float f; uint32_t u; } v; v.f = f;
  uint32_t r = (v.u + 0x7FFFu + ((v.u >> 16) & 1u)) >> 16;  // RNE
  return (short)(uint16_t)r;
}

static __device__ __forceinline__ float bf2f(short s) {
  union { uint32_t u; float f; } v;
  v.u = ((uint32_t)(uint16_t)s) << 16;
  return v.f;
}

static __device__ __forceinline__ void gload_lds16(const void* g, void* s) {
  __builtin_amdgcn_global_load_lds(
      (const __attribute__((address_space(1))) uint32_t*)g,
      (__attribute__((address_space(3))) uint32_t*)s, 16, 0, 0);
}

// ---------------------------------------------------------------- f32 -> bf16, 3 activation tensors (4M elems each)
__global__ void k_cvt3(const float* __restrict__ a, const float* __restrict__ b,
                       const float* __restrict__ c,
                       short* __restrict__ o0, short* __restrict__ o1,
                       short* __restrict__ o2) {
  const int i = (blockIdx.x * 256 + threadIdx.x) * 4;
  const float* src; short* dst;
  switch (blockIdx.y) {
    case 0: src = a; dst = o0; break;
    case 1: src = b; dst = o1; break;
    default: src = c; dst = o2; break;
  }
  f32x4 v = *(const f32x4*)(src + i);
  s16x4 o;
  o.x = f2bf(v.x); o.y = f2bf(v.y); o.z = f2bf(v.z); o.w = f2bf(v.w);
  *(s16x4*)(dst + i) = o;
}

// ---------------------------------------------------------------- f32 -> bf16, 4 weight matrices (1M elems each)
__global__ void k_cvt4(const float* __restrict__ a, const float* __restrict__ b,
                       const float* __restrict__ c, const float* __restrict__ d,
                       short* __restrict__ o0, short* __restrict__ o1,
                       short* __restrict__ o2, short* __restrict__ o3) {
  const int i = (blockIdx.x * 256 + threadIdx.x) * 4;
  const float* src; short* dst;
  switch (blockIdx.y) {
    case 0: src = a; dst = o0; break;
    case 1: src = b; dst = o1; break;
    case 2: src = c; dst = o2; break;
    default: src = d; dst = o3; break;
  }
  f32x4 v = *(const f32x4*)(src + i);
  s16x4 o;
  o.x = f2bf(v.x); o.y = f2bf(v.y); o.z = f2bf(v.z); o.w = f2bf(v.w);
  *(s16x4*)(dst + i) = o;
}

// ---------------------------------------------------------------- GEMM core (R15/R17 structure)
// C[m][n] = sum_k A[m][k] * Bw[n][k] + bias[n]; BM=BN=128, BK=64.
// LDS 16B-chunk XOR swizzle via pre-swizzled gload_lds source (async path —
// R16 lesson: reg-staging cvt fusion is 2.5x slower, keep global_load_lds).
static __device__ __forceinline__ void gemm_body(
    const short* __restrict__ A, const short* __restrict__ Bw,
    const float* __restrict__ bias, void* __restrict__ outp, int mode,
    short* As, short* Bs, int m0, int n0) {
  const int tid = threadIdx.x;
  const int w = tid >> 6, l = tid & 63;
  const int wm = w >> 1, wn = w & 1;
  const int lr = l & 15, lg = l >> 4;

  f32x4 acc[4][4] = {};

  for (int kt = 0; kt < 16; ++kt) {
    __syncthreads();
#pragma unroll
    for (int q = 0; q < 4; ++q) {
      const int slot = (w * 4 + q) * 64 + l;   // 16B slot index in tile
      const int row = slot >> 3;               // 8 chunks per 128B row
      const int chunk = (slot & 7) ^ (row & 7);
      const size_t goff = (size_t)row * 1024 + (size_t)kt * 64 + chunk * 8;
      gload_lds16(A + (size_t)m0 * 1024 + goff, (char*)As + (w * 4 + q) * 1024);
      gload_lds16(Bw + (size_t)n0 * 1024 + goff, (char*)Bs + (w * 4 + q) * 1024);
    }
    asm volatile("s_waitcnt vmcnt(0)");
    __syncthreads();
#pragma unroll
    for (int ks = 0; ks < 2; ++ks) {
      s16x8 af[4], bfr[4];
#pragma unroll
      for (int mi = 0; mi < 4; ++mi) {
        const int row = wm * 64 + mi * 16 + lr;
        const int chunk = (ks * 4 + lg) ^ (row & 7);
        af[mi] = *(const s16x8*)(As + row * 64 + chunk * 8);
      }
#pragma unroll
      for (int ni = 0; ni < 4; ++ni) {
        const int row = wn * 64 + ni * 16 + lr;
        const int chunk = (ks * 4 + lg) ^ (row & 7);
        bfr[ni] = *(const s16x8*)(Bs + row * 64 + chunk * 8);
      }
#pragma unroll
      for (int mi = 0; mi < 4; ++mi)
#pragma unroll
        for (int ni = 0; ni < 4; ++ni)
          acc[mi][ni] = MFMA(af[mi], bfr[ni], acc[mi][ni]);
    }
  }

  // Epilogue. C frag: row=(lg*4+r), col=lr within each 16x16.
#pragma unroll
  for (int mi = 0; mi < 4; ++mi) {
#pragma unroll
    for (int ni = 0; ni < 4; ++ni) {
      const int gm0 = m0 + wm * 64 + mi * 16 + lg * 4;
      const int gc = n0 + wn * 64 + ni * 16 + lr;
      const float bv = bias[gc];
      if (mode == 2) {
        float* o = (float*)outp;
#pragma unroll
        for (int r = 0; r < 4; ++r)
          o[(size_t)(gm0 + r) * 1024 + gc] = acc[mi][ni][r] + bv;
      } else if (mode == 0) {
        short* o = (short*)outp;
        const int h = gc >> 6, d = gc & 63;
#pragma unroll
        for (int r = 0; r < 4; ++r) {
          const int gm = gm0 + r;
          const int b = gm >> 10, np = gm & 1023;
          o[((size_t)(b * 16 + h) * 1024 + np) * 64 + d] = f2bf(acc[mi][ni][r] + bv);
        }
      } else {  // mode 1: transposed V, pack 4 consecutive n-positions as 8B store
        short* o = (short*)outp;
        const int h = gc >> 6, d = gc & 63;
        const int b = gm0 >> 10, np0 = gm0 & 1023;
        s16x4 pk;
        pk.x = f2bf(acc[mi][ni][0] + bv);
        pk.y = f2bf(acc[mi][ni][1] + bv);
        pk.z = f2bf(acc[mi][ni][2] + bv);
        pk.w = f2bf(acc[mi][ni][3] + bv);
        *(s16x4*)(o + ((size_t)(b * 16 + h) * 64 + d) * 1024 + np0) = pk;
      }
    }
  }
}

// R18: the 3 projection GEMMs merged into ONE 768-block launch (gridDim.z
// selects Q/K/V). R17 ran them serially at 256 blocks = 1 block/CU =
// 1 wave/SIMD — the K-loop's vmcnt(0)+barrier stall had zero other-wave
// cover (latency-bound, m102 small-shape signature). 3 blocks/CU gives the
// scheduler cross-block overlap on the same code.
__global__ __launch_bounds__(256, 2) void k_gemm3(
    const short* __restrict__ Xq, const short* __restrict__ Xk,
    const short* __restrict__ Xv,
    const short* __restrict__ WqB, const short* __restrict__ WkB,
    const short* __restrict__ WvB,
    const float* __restrict__ bq, const float* __restrict__ bk,
    const float* __restrict__ bv,
    short* __restrict__ qws, short* __restrict__ kws, short* __restrict__ vtw) {
  __shared__ short As[128 * 64];
  __shared__ short Bs[128 * 64];
  const short* A; const short* Bw; const float* bias; short* outp; int mode;
  switch (blockIdx.z) {
    case 0:  A = Xq; Bw = WqB; bias = bq; outp = qws; mode = 0; break;
    case 1:  A = Xk; Bw = WkB; bias = bk; outp = kws; mode = 0; break;
    default: A = Xv; Bw = WvB; bias = bv; outp = vtw; mode = 1; break;
  }
  gemm_body(A, Bw, bias, outp, mode, As, Bs, blockIdx.x * 128, blockIdx.y * 128);
}

__global__ __launch_bounds__(256, 2) void k_gemm(
    const short* __restrict__ A, const short* __restrict__ Bw,
    const float* __restrict__ bias, void* __restrict__ outp, int mode) {
  __shared__ short As[128 * 64];
  __shared__ short Bs[128 * 64];
  gemm_body(A, Bw, bias, outp, mode, As, Bs, blockIdx.x * 128, blockIdx.y * 128);
}

// ---------------------------------------------------------------- fused attention (no-split flash, rotated kt-walk)
// R15 champion, byte-identical. Grid (NQ/64, B*H); 4 waves; wave owns 16
// q-rows; walks all 16 key-tiles with per-BLOCK kt-rotation (breaks lockstep
// channel camping, +13% R9). Falsified levers: occupancy (21-46% neutral),
// register pipelining, vectorization, burst shape, phase separation, NT
// hints, per-wave rotation. k_attn sits at ~2.9 TB/s on its mandatory
// ~700MB mixed stream — practical wall.
__global__ __launch_bounds__(256, 3) void k_attn(
    const short* __restrict__ qws, const short* __restrict__ kws,
    const short* __restrict__ vtws,
    const float* __restrict__ attw, const int* __restrict__ attm,
    float* __restrict__ att_map, short* __restrict__ aout) {
  __shared__ f32x4 s_lds[4 * 256];       // per wave: 16 rows x 16 f32x4 chunks (4KB)
  __shared__ short p_lds[4 * 16 * 64];   // per wave: 16 x 64 bf16 (2KB), swizzled
  __shared__ float st_lds[4 * 16];       // per wave: per-row corr / inv broadcast
  const int tid = threadIdx.x;
  const int w = tid >> 6, l = tid & 63;
  const int lr = l & 15, lg = l >> 4;
  const int bh = blockIdx.y;                 // b*16 + h
  const int q0 = blockIdx.x * 64 + w * 16;   // this wave's first q row
  f32x4* const sw = s_lds + w * 256;
  char* const pw = (char*)p_lds + w * 2048;
  float* const stw = st_lds + w * 16;

  // Q fragments (B-operand of swapped QK^T: col = lr = q, kk = lg*8 + j)
  const short* qb = qws + ((size_t)bh * NQ_ + q0 + lr) * 64 + lg * 8;
  const s16x8 qf0 = *(const s16x8*)(qb);
  const s16x8 qf1 = *(const s16x8*)(qb + 32);

  f32x4 o[4] = {};
  float m4[4], l4[4];                    // linear-domain state: row = it*4 + lg
#pragma unroll
  for (int it = 0; it < 4; ++it) { m4[it] = -3.0e38f; l4[it] = 0.0f; }

  // linear-domain global base: row q0 + lg (+ it*4), col lr*4
  const size_t linBase = ((size_t)bh * NQ_ + q0 + lg) * (size_t)NK_ + lr * 4;

  const int rot = (blockIdx.x + bh) & 15;  // per-BLOCK kt-phase decorrelation

  for (int t = 0; t < 16; ++t) {
    const int kt = (rot + t) & 15;
    // ---- S^T = K Q^T: lane holds S[k=fn*16+lg*4+{0..3}][q=lr]
    f32x4 s[4];
    const short* kb0 = kws + ((size_t)bh * NK_ + kt * 64 + lr) * 64 + lg * 8;
#pragma unroll
    for (int fn = 0; fn < 4; ++fn) {
      const short* kb = kb0 + fn * 1024;
      f32x4 z = {};
      z = MFMA(*(const s16x8*)kb, qf0, z);
      z = MFMA(*(const s16x8*)(kb + 32), qf1, z);
      s[fn] = z;
    }
    // ---- S -> per-wave LDS: row = q = lr, k-chunk = fn*4+lg, swizzle ^row
#pragma unroll
    for (int fn = 0; fn < 4; ++fn)
      sw[lr * 16 + ((fn * 4 + lg) ^ lr)] = s[fn];
    asm volatile("s_waitcnt lgkmcnt(0)" ::: "memory");
    __builtin_amdgcn_sched_barrier(0);
    // ---- linear phase: issue all S reads + att loads up front (MLP)
    f32x4 sv4[4], wv4[4];
    s32x4 mv4[4];
#pragma unroll
    for (int it = 0; it < 4; ++it) {
      const int q = it * 4 + lg;
      sv4[it] = sw[q * 16 + (lr ^ q)];
      const size_t ga = linBase + (size_t)(it * 4) * NK_ + kt * 64;
      wv4[it] = *(const f32x4*)(attw + ga);
      mv4[it] = *(const s32x4*)(attm + ga);
    }
#pragma unroll
    for (int it = 0; it < 4; ++it) {
      const int q = it * 4 + lg;
      f32x4 sv;
#pragma unroll
      for (int j = 0; j < 4; ++j) sv[j] = sv4[it][j] * 0.125f;
      const size_t ga = linBase + (size_t)(it * 4) * NK_ + kt * 64;
      *(f32x4*)(att_map + ga) = sv;            // 256B-contiguous per 16-lane group
      float p[4];
#pragma unroll
      for (int j = 0; j < 4; ++j)
        p[j] = mv4[it][j] ? sv[j] * wv4[it][j] : -1.0e30f;
      // row reduce within the 16 consecutive lanes owning this row
      float t2 = fmaxf(fmaxf(p[0], p[1]), fmaxf(p[2], p[3]));
      t2 = fmaxf(t2, __shfl_xor(t2, 1, 64));
      t2 = fmaxf(t2, __shfl_xor(t2, 2, 64));
      t2 = fmaxf(t2, __shfl_xor(t2, 4, 64));
      t2 = fmaxf(t2, __shfl_xor(t2, 8, 64));
      const float mn = fmaxf(m4[it], t2);
      const float corr = __expf(m4[it] - mn);
      m4[it] = mn;
      float rs = 0.0f;
#pragma unroll
      for (int j = 0; j < 4; ++j) { p[j] = __expf(p[j] - mn); rs += p[j]; }
      rs += __shfl_xor(rs, 1, 64);
      rs += __shfl_xor(rs, 2, 64);
      rs += __shfl_xor(rs, 4, 64);
      rs += __shfl_xor(rs, 8, 64);
      l4[it] = l4[it] * corr + rs;
      // P (bf16) -> p_lds in A-operand layout [q][k], 16B-chunk XOR swizzle
      s16x4 pk;
      pk.x = f2bf(p[0]); pk.y = f2bf(p[1]); pk.z = f2bf(p[2]); pk.w = f2bf(p[3]);
      *(s16x4*)(pw + q * 128 + (((lr >> 1) ^ (q & 7)) << 4) + (lr & 1) * 8) = pk;
      if (lr == 0) stw[q] = corr;              // per-row corr broadcast
    }
    asm volatile("s_waitcnt lgkmcnt(0)" ::: "memory");
    __builtin_amdgcn_sched_barrier(0);
    // ---- o rescale: o rows are q = lg*4 + r (MFMA C layout)
#pragma unroll
    for (int r = 0; r < 4; ++r) {
      const float cr = stw[lg * 4 + r];        // same-address broadcast per lg
      o[0][r] *= cr; o[1][r] *= cr; o[2][r] *= cr; o[3][r] *= cr;
    }
    // ---- PV: o += P @ V  (A = P rows q=lr, B = V^T rows dv=lr)
    const short* vb0 = vtws + ((size_t)bh * 64 + lr) * (size_t)NK_ + (size_t)kt * 64 + lg * 8;
#pragma unroll
    for (int ks = 0; ks < 2; ++ks) {
      const int chunk = (ks * 4 + lg) ^ (lr & 7);
      const s16x8 pa = *(const s16x8*)(pw + lr * 128 + chunk * 16);
#pragma unroll
      for (int g = 0; g < 4; ++g) {
        const s16x8 vf = *(const s16x8*)(vb0 + (size_t)g * 16 * NK_ + ks * 32);
        o[g] = MFMA(pa, vf, o[g]);
      }
    }
  }

  // ---- normalize and write attention output (B, NQ, H*64) bf16
  if (lr == 0) {
#pragma unroll
    for (int it = 0; it < 4; ++it) stw[it * 4 + lg] = 1.0f / l4[it];
  }
  asm volatile("s_waitcnt lgkmcnt(0)" ::: "memory");
  __builtin_amdgcn_sched_barrier(0);
  const int b = bh >> 4, h = bh & 15;
#pragma unroll
  for (int r = 0; r < 4; ++r) {
    const float inv = stw[lg * 4 + r];
    const size_t orow = ((size_t)b * NQ_ + q0 + lg * 4 + r) * 1024 + h * 64 + lr;
#pragma unroll
    for (int g = 0; g < 4; ++g)
      aout[orow + g * 16] = f2bf(o[g][r] * inv);
  }
}

// ---------------------------------------------------------------- launch
extern "C" void kernel_launch(void* const* d_in, const int* in_sizes, int n_in,
                              void* d_out, int out_size, void* d_ws, size_t ws_size,
                              hipStream_t stream) {
  const float* queries = (const float*)d_in[0];
  const float* keys    = (const float*)d_in[1];
  const float* values  = (const float*)d_in[2];
  const float* attw    = (const float*)d_in[3];
  const int*   attm    = (const int*)d_in[4];
  const float* Wq = (const float*)d_in[5];
  const float* bq = (const float*)d_in[6];
  const float* Wk = (const float*)d_in[7];
  const float* bk = (const float*)d_in[8];
  const float* Wv = (const float*)d_in[9];
  const float* bv = (const float*)d_in[10];
  const float* Wo = (const float*)d_in[11];
  const float* bo = (const float*)d_in[12];

  float* out = (float*)d_out;                              // (4,1024,1024)
  float* att_map = out + (size_t)B_ * NQ_ * DM_;           // (4,16,1024,1024)

  // Workspace layout (shorts). Total ~64 MB.
  short* ws  = (short*)d_ws;
  short* WqB = ws;                   // 1024*1024 each
  short* WkB = WqB + 1048576;
  short* WvB = WkB + 1048576;
  short* WoB = WvB + 1048576;
  short* Xq  = WoB + 1048576;        // 4096*1024 each
  short* Xk  = Xq + 4194304;
  short* Xv  = Xk + 4194304;
  short* qws = Xv + 4194304;         // (B,H,NQ,64)
  short* kws = qws + 4194304;        // (B,H,NK,64)
  short* vtw = kws + 4194304;        // (B,H,64,NK)
  short* aout = vtw + 4194304;       // (B*NQ, H*64)

  // cvt: 2 launches total (3 activations; 4 weights)
  k_cvt3<<<dim3(4096, 3), 256, 0, stream>>>(queries, keys, values, Xq, Xk, Xv);
  k_cvt4<<<dim3(1024, 4), 256, 0, stream>>>(Wq, Wk, Wv, Wo, WqB, WkB, WvB, WoB);

  // 3 projection GEMMs in ONE launch (768 blocks = 3/CU)
  k_gemm3<<<dim3(32, 8, 3), 256, 0, stream>>>(Xq, Xk, Xv, WqB, WkB, WvB,
                                              bq, bk, bv, qws, kws, vtw);

  dim3 ga(16, 64);
  k_attn<<<ga, 256, 0, stream>>>(qws, kws, vtw, attw, attm, att_map, aout);

  k_gemm<<<dim3(32, 8), 256, 0, stream>>>(aout, WoB, bo, out, 2);
}

// Round 19
// 307.223 us; speedup vs baseline: 1.6109x; 1.0029x over previous
//
#include <hip/hip_runtime.h>
#include <stdint.h>
#include <math.h>

// Problem constants
#define B_ 4
#define H_ 16
#define DM_ 1024
#define NQ_ 1024
#define NK_ 1024
// D_K = D_V = 64

typedef __attribute__((ext_vector_type(4))) float f32x4;
typedef __attribute__((ext_vector_type(4))) int   s32x4;
typedef __attribute__((ext_vector_type(4))) short s16x4;
typedef __attribute__((ext_vector_type(8))) short s16x8;

#define MFMA(a, b, c) __builtin_amdgcn_mfma_f32_16x16x32_bf16(a, b, c, 0, 0, 0)

static __device__ __forceinline__ short f2bf(float f) {
  union { float f; uint32_t u; } v; v.f = f;
  uint32_t r = (v.u + 0x7FFFu + ((v.u >> 16) & 1u)) >> 16;  // RNE
  return (short)(uint16_t)r;
}

static __device__ __forceinline__ float bf2f(short s) {
  union { uint32_t u; float f; } v;
  v.u = ((uint32_t)(uint16_t)s) << 16;
  return v.f;
}

static __device__ __forceinline__ void gload_lds16(const void* g, void* s) {
  __builtin_amdgcn_global_load_lds(
      (const __attribute__((address_space(1))) uint32_t*)g,
      (__attribute__((address_space(3))) uint32_t*)s, 16, 0, 0);
}

// ---------------------------------------------------------------- f32 -> bf16, ALL 7 tensors, one launch
// blocks 0..12287: activations q/k/v (4096 blocks each, 4M elems each)
// blocks 12288..16383: weights Wq/Wk/Wv/Wo (1024 blocks each, 1M elems each)
__global__ void k_cvt7(const float* __restrict__ q, const float* __restrict__ k,
                       const float* __restrict__ v,
                       const float* __restrict__ wq, const float* __restrict__ wk,
                       const float* __restrict__ wv, const float* __restrict__ wo,
                       short* __restrict__ oq, short* __restrict__ ok,
                       short* __restrict__ ov,
                       short* __restrict__ owq, short* __restrict__ owk,
                       short* __restrict__ owv, short* __restrict__ owo) {
  const int blk = blockIdx.x;
  const float* src; short* dst; int base;
  if (blk < 12288) {
    const int t = blk >> 12;             // /4096
    base = (blk & 4095) * 1024;
    switch (t) {
      case 0: src = q; dst = oq; break;
      case 1: src = k; dst = ok; break;
      default: src = v; dst = ov; break;
    }
  } else {
    const int t = (blk - 12288) >> 10;   // /1024
    base = ((blk - 12288) & 1023) * 1024;
    switch (t) {
      case 0: src = wq; dst = owq; break;
      case 1: src = wk; dst = owk; break;
      case 2: src = wv; dst = owv; break;
      default: src = wo; dst = owo; break;
    }
  }
  const int i = base + threadIdx.x * 4;
  f32x4 val = *(const f32x4*)(src + i);
  s16x4 o;
  o.x = f2bf(val.x); o.y = f2bf(val.y); o.z = f2bf(val.z); o.w = f2bf(val.w);
  *(s16x4*)(dst + i) = o;
}

// ---------------------------------------------------------------- GEMM core (R15/R17 structure)
// C[m][n] = sum_k A[m][k] * Bw[n][k] + bias[n]; BM=BN=128, BK=64.
// LDS 16B-chunk XOR swizzle via pre-swizzled gload_lds source (async path —
// R16 lesson: reg-staging cvt fusion is 2.5x slower, keep global_load_lds).
static __device__ __forceinline__ void gemm_body(
    const short* __restrict__ A, const short* __restrict__ Bw,
    const float* __restrict__ bias, void* __restrict__ outp, int mode,
    short* As, short* Bs, int m0, int n0) {
  const int tid = threadIdx.x;
  const int w = tid >> 6, l = tid & 63;
  const int wm = w >> 1, wn = w & 1;
  const int lr = l & 15, lg = l >> 4;

  f32x4 acc[4][4] = {};

  for (int kt = 0; kt < 16; ++kt) {
    __syncthreads();
#pragma unroll
    for (int q = 0; q < 4; ++q) {
      const int slot = (w * 4 + q) * 64 + l;   // 16B slot index in tile
      const int row = slot >> 3;               // 8 chunks per 128B row
      const int chunk = (slot & 7) ^ (row & 7);
      const size_t goff = (size_t)row * 1024 + (size_t)kt * 64 + chunk * 8;
      gload_lds16(A + (size_t)m0 * 1024 + goff, (char*)As + (w * 4 + q) * 1024);
      gload_lds16(Bw + (size_t)n0 * 1024 + goff, (char*)Bs + (w * 4 + q) * 1024);
    }
    asm volatile("s_waitcnt vmcnt(0)");
    __syncthreads();
#pragma unroll
    for (int ks = 0; ks < 2; ++ks) {
      s16x8 af[4], bfr[4];
#pragma unroll
      for (int mi = 0; mi < 4; ++mi) {
        const int row = wm * 64 + mi * 16 + lr;
        const int chunk = (ks * 4 + lg) ^ (row & 7);
        af[mi] = *(const s16x8*)(As + row * 64 + chunk * 8);
      }
#pragma unroll
      for (int ni = 0; ni < 4; ++ni) {
        const int row = wn * 64 + ni * 16 + lr;
        const int chunk = (ks * 4 + lg) ^ (row & 7);
        bfr[ni] = *(const s16x8*)(Bs + row * 64 + chunk * 8);
      }
#pragma unroll
      for (int mi = 0; mi < 4; ++mi)
#pragma unroll
        for (int ni = 0; ni < 4; ++ni)
          acc[mi][ni] = MFMA(af[mi], bfr[ni], acc[mi][ni]);
    }
  }

  // Epilogue. C frag: row=(lg*4+r), col=lr within each 16x16.
#pragma unroll
  for (int mi = 0; mi < 4; ++mi) {
#pragma unroll
    for (int ni = 0; ni < 4; ++ni) {
      const int gm0 = m0 + wm * 64 + mi * 16 + lg * 4;
      const int gc = n0 + wn * 64 + ni * 16 + lr;
      const float bv = bias[gc];
      if (mode == 2) {
        float* o = (float*)outp;
#pragma unroll
        for (int r = 0; r < 4; ++r)
          o[(size_t)(gm0 + r) * 1024 + gc] = acc[mi][ni][r] + bv;
      } else if (mode == 0) {
        short* o = (short*)outp;
        const int h = gc >> 6, d = gc & 63;
#pragma unroll
        for (int r = 0; r < 4; ++r) {
          const int gm = gm0 + r;
          const int b = gm >> 10, np = gm & 1023;
          o[((size_t)(b * 16 + h) * 1024 + np) * 64 + d] = f2bf(acc[mi][ni][r] + bv);
        }
      } else {  // mode 1: transposed V, pack 4 consecutive n-positions as 8B store
        short* o = (short*)outp;
        const int h = gc >> 6, d = gc & 63;
        const int b = gm0 >> 10, np0 = gm0 & 1023;
        s16x4 pk;
        pk.x = f2bf(acc[mi][ni][0] + bv);
        pk.y = f2bf(acc[mi][ni][1] + bv);
        pk.z = f2bf(acc[mi][ni][2] + bv);
        pk.w = f2bf(acc[mi][ni][3] + bv);
        *(s16x4*)(o + ((size_t)(b * 16 + h) * 64 + d) * 1024 + np0) = pk;
      }
    }
  }
}

// 3 projection GEMMs in ONE 768-block launch (3 blocks/CU — R18 win: at 256
// blocks = 1/CU the vmcnt(0)+barrier stalls had zero other-wave cover).
__global__ __launch_bounds__(256, 2) void k_gemm3(
    const short* __restrict__ Xq, const short* __restrict__ Xk,
    const short* __restrict__ Xv,
    const short* __restrict__ WqB, const short* __restrict__ WkB,
    const short* __restrict__ WvB,
    const float* __restrict__ bq, const float* __restrict__ bk,
    const float* __restrict__ bv,
    short* __restrict__ qws, short* __restrict__ kws, short* __restrict__ vtw) {
  __shared__ short As[128 * 64];
  __shared__ short Bs[128 * 64];
  const short* A; const short* Bw; const float* bias; short* outp; int mode;
  switch (blockIdx.z) {
    case 0:  A = Xq; Bw = WqB; bias = bq; outp = qws; mode = 0; break;
    case 1:  A = Xk; Bw = WkB; bias = bk; outp = kws; mode = 0; break;
    default: A = Xv; Bw = WvB; bias = bv; outp = vtw; mode = 1; break;
  }
  gemm_body(A, Bw, bias, outp, mode, As, Bs, blockIdx.x * 128, blockIdx.y * 128);
}

__global__ __launch_bounds__(256, 2) void k_gemm(
    const short* __restrict__ A, const short* __restrict__ Bw,
    const float* __restrict__ bias, void* __restrict__ outp, int mode) {
  __shared__ short As[128 * 64];
  __shared__ short Bs[128 * 64];
  gemm_body(A, Bw, bias, outp, mode, As, Bs, blockIdx.x * 128, blockIdx.y * 128);
}

// ---------------------------------------------------------------- fused attention (no-split flash, rotated kt-walk)
// R15 champion, byte-identical. Grid (NQ/64, B*H); 4 waves; wave owns 16
// q-rows; walks all 16 key-tiles with per-BLOCK kt-rotation (breaks lockstep
// channel camping, +13% R9). Falsified levers: occupancy (21-46% neutral),
// register pipelining, vectorization, burst shape, phase separation, NT
// hints, per-wave rotation. k_attn sits at ~2.9 TB/s on its mandatory
// ~700MB mixed stream — practical wall.
__global__ __launch_bounds__(256, 3) void k_attn(
    const short* __restrict__ qws, const short* __restrict__ kws,
    const short* __restrict__ vtws,
    const float* __restrict__ attw, const int* __restrict__ attm,
    float* __restrict__ att_map, short* __restrict__ aout) {
  __shared__ f32x4 s_lds[4 * 256];       // per wave: 16 rows x 16 f32x4 chunks (4KB)
  __shared__ short p_lds[4 * 16 * 64];   // per wave: 16 x 64 bf16 (2KB), swizzled
  __shared__ float st_lds[4 * 16];       // per wave: per-row corr / inv broadcast
  const int tid = threadIdx.x;
  const int w = tid >> 6, l = tid & 63;
  const int lr = l & 15, lg = l >> 4;
  const int bh = blockIdx.y;                 // b*16 + h
  const int q0 = blockIdx.x * 64 + w * 16;   // this wave's first q row
  f32x4* const sw = s_lds + w * 256;
  char* const pw = (char*)p_lds + w * 2048;
  float* const stw = st_lds + w * 16;

  // Q fragments (B-operand of swapped QK^T: col = lr = q, kk = lg*8 + j)
  const short* qb = qws + ((size_t)bh * NQ_ + q0 + lr) * 64 + lg * 8;
  const s16x8 qf0 = *(const s16x8*)(qb);
  const s16x8 qf1 = *(const s16x8*)(qb + 32);

  f32x4 o[4] = {};
  float m4[4], l4[4];                    // linear-domain state: row = it*4 + lg
#pragma unroll
  for (int it = 0; it < 4; ++it) { m4[it] = -3.0e38f; l4[it] = 0.0f; }

  // linear-domain global base: row q0 + lg (+ it*4), col lr*4
  const size_t linBase = ((size_t)bh * NQ_ + q0 + lg) * (size_t)NK_ + lr * 4;

  const int rot = (blockIdx.x + bh) & 15;  // per-BLOCK kt-phase decorrelation

  for (int t = 0; t < 16; ++t) {
    const int kt = (rot + t) & 15;
    // ---- S^T = K Q^T: lane holds S[k=fn*16+lg*4+{0..3}][q=lr]
    f32x4 s[4];
    const short* kb0 = kws + ((size_t)bh * NK_ + kt * 64 + lr) * 64 + lg * 8;
#pragma unroll
    for (int fn = 0; fn < 4; ++fn) {
      const short* kb = kb0 + fn * 1024;
      f32x4 z = {};
      z = MFMA(*(const s16x8*)kb, qf0, z);
      z = MFMA(*(const s16x8*)(kb + 32), qf1, z);
      s[fn] = z;
    }
    // ---- S -> per-wave LDS: row = q = lr, k-chunk = fn*4+lg, swizzle ^row
#pragma unroll
    for (int fn = 0; fn < 4; ++fn)
      sw[lr * 16 + ((fn * 4 + lg) ^ lr)] = s[fn];
    asm volatile("s_waitcnt lgkmcnt(0)" ::: "memory");
    __builtin_amdgcn_sched_barrier(0);
    // ---- linear phase: issue all S reads + att loads up front (MLP)
    f32x4 sv4[4], wv4[4];
    s32x4 mv4[4];
#pragma unroll
    for (int it = 0; it < 4; ++it) {
      const int q = it * 4 + lg;
      sv4[it] = sw[q * 16 + (lr ^ q)];
      const size_t ga = linBase + (size_t)(it * 4) * NK_ + kt * 64;
      wv4[it] = *(const f32x4*)(attw + ga);
      mv4[it] = *(const s32x4*)(attm + ga);
    }
#pragma unroll
    for (int it = 0; it < 4; ++it) {
      const int q = it * 4 + lg;
      f32x4 sv;
#pragma unroll
      for (int j = 0; j < 4; ++j) sv[j] = sv4[it][j] * 0.125f;
      const size_t ga = linBase + (size_t)(it * 4) * NK_ + kt * 64;
      *(f32x4*)(att_map + ga) = sv;            // 256B-contiguous per 16-lane group
      float p[4];
#pragma unroll
      for (int j = 0; j < 4; ++j)
        p[j] = mv4[it][j] ? sv[j] * wv4[it][j] : -1.0e30f;
      // row reduce within the 16 consecutive lanes owning this row
      float t2 = fmaxf(fmaxf(p[0], p[1]), fmaxf(p[2], p[3]));
      t2 = fmaxf(t2, __shfl_xor(t2, 1, 64));
      t2 = fmaxf(t2, __shfl_xor(t2, 2, 64));
      t2 = fmaxf(t2, __shfl_xor(t2, 4, 64));
      t2 = fmaxf(t2, __shfl_xor(t2, 8, 64));
      const float mn = fmaxf(m4[it], t2);
      const float corr = __expf(m4[it] - mn);
      m4[it] = mn;
      float rs = 0.0f;
#pragma unroll
      for (int j = 0; j < 4; ++j) { p[j] = __expf(p[j] - mn); rs += p[j]; }
      rs += __shfl_xor(rs, 1, 64);
      rs += __shfl_xor(rs, 2, 64);
      rs += __shfl_xor(rs, 4, 64);
      rs += __shfl_xor(rs, 8, 64);
      l4[it] = l4[it] * corr + rs;
      // P (bf16) -> p_lds in A-operand layout [q][k], 16B-chunk XOR swizzle
      s16x4 pk;
      pk.x = f2bf(p[0]); pk.y = f2bf(p[1]); pk.z = f2bf(p[2]); pk.w = f2bf(p[3]);
      *(s16x4*)(pw + q * 128 + (((lr >> 1) ^ (q & 7)) << 4) + (lr & 1) * 8) = pk;
      if (lr == 0) stw[q] = corr;              // per-row corr broadcast
    }
    asm volatile("s_waitcnt lgkmcnt(0)" ::: "memory");
    __builtin_amdgcn_sched_barrier(0);
    // ---- o rescale: o rows are q = lg*4 + r (MFMA C layout)
#pragma unroll
    for (int r = 0; r < 4; ++r) {
      const float cr = stw[lg * 4 + r];        // same-address broadcast per lg
      o[0][r] *= cr; o[1][r] *= cr; o[2][r] *= cr; o[3][r] *= cr;
    }
    // ---- PV: o += P @ V  (A = P rows q=lr, B = V^T rows dv=lr)
    const short* vb0 = vtws + ((size_t)bh * 64 + lr) * (size_t)NK_ + (size_t)kt * 64 + lg * 8;
#pragma unroll
    for (int ks = 0; ks < 2; ++ks) {
      const int chunk = (ks * 4 + lg) ^ (lr & 7);
      const s16x8 pa = *(const s16x8*)(pw + lr * 128 + chunk * 16);
#pragma unroll
      for (int g = 0; g < 4; ++g) {
        const s16x8 vf = *(const s16x8*)(vb0 + (size_t)g * 16 * NK_ + ks * 32);
        o[g] = MFMA(pa, vf, o[g]);
      }
    }
  }

  // ---- normalize and write attention output (B, NQ, H*64) bf16
  if (lr == 0) {
#pragma unroll
    for (int it = 0; it < 4; ++it) stw[it * 4 + lg] = 1.0f / l4[it];
  }
  asm volatile("s_waitcnt lgkmcnt(0)" ::: "memory");
  __builtin_amdgcn_sched_barrier(0);
  const int b = bh >> 4, h = bh & 15;
#pragma unroll
  for (int r = 0; r < 4; ++r) {
    const float inv = stw[lg * 4 + r];
    const size_t orow = ((size_t)b * NQ_ + q0 + lg * 4 + r) * 1024 + h * 64 + lr;
#pragma unroll
    for (int g = 0; g < 4; ++g)
      aout[orow + g * 16] = f2bf(o[g][r] * inv);
  }
}

// ---------------------------------------------------------------- launch
extern "C" void kernel_launch(void* const* d_in, const int* in_sizes, int n_in,
                              void* d_out, int out_size, void* d_ws, size_t ws_size,
                              hipStream_t stream) {
  const float* queries = (const float*)d_in[0];
  const float* keys    = (const float*)d_in[1];
  const float* values  = (const float*)d_in[2];
  const float* attw    = (const float*)d_in[3];
  const int*   attm    = (const int*)d_in[4];
  const float* Wq = (const float*)d_in[5];
  const float* bq = (const float*)d_in[6];
  const float* Wk = (const float*)d_in[7];
  const float* bk = (const float*)d_in[8];
  const float* Wv = (const float*)d_in[9];
  const float* bv = (const float*)d_in[10];
  const float* Wo = (const float*)d_in[11];
  const float* bo = (const float*)d_in[12];

  float* out = (float*)d_out;                              // (4,1024,1024)
  float* att_map = out + (size_t)B_ * NQ_ * DM_;           // (4,16,1024,1024)

  // Workspace layout (shorts). Total ~64 MB.
  short* ws  = (short*)d_ws;
  short* WqB = ws;                   // 1024*1024 each
  short* WkB = WqB + 1048576;
  short* WvB = WkB + 1048576;
  short* WoB = WvB + 1048576;
  short* Xq  = WoB + 1048576;        // 4096*1024 each
  short* Xk  = Xq + 4194304;
  short* Xv  = Xk + 4194304;
  short* qws = Xv + 4194304;         // (B,H,NQ,64)
  short* kws = qws + 4194304;        // (B,H,NK,64)
  short* vtw = kws + 4194304;        // (B,H,64,NK)
  short* aout = vtw + 4194304;       // (B*NQ, H*64)

  // all 7 f32->bf16 conversions in ONE launch
  k_cvt7<<<16384, 256, 0, stream>>>(queries, keys, values, Wq, Wk, Wv, Wo,
                                    Xq, Xk, Xv, WqB, WkB, WvB, WoB);

  // 3 projection GEMMs in ONE launch (768 blocks = 3/CU)
  k_gemm3<<<dim3(32, 8, 3), 256, 0, stream>>>(Xq, Xk, Xv, WqB, WkB, WvB,
                                              bq, bk, bv, qws, kws, vtw);

  dim3 ga(16, 64);
  k_attn<<<ga, 256, 0, stream>>>(qws, kws, vtw, attw, attm, att_map, aout);

  k_gemm<<<dim3(32, 8), 256, 0, stream>>>(aout, WoB, bo, out, 2);
}